// Round 1
// baseline (1200.106 us; speedup 1.0000x reference)
//
#include <hip/hip_runtime.h>
#include <cstdint>

#define BB 64
#define SS 512
#define HH 512
#define EE 512

typedef _Float16 h2_t __attribute__((ext_vector_type(2)));

__device__ __forceinline__ float fdot2(uint32_t a, uint32_t b, float c) {
    return __builtin_amdgcn_fdot2(__builtin_bit_cast(h2_t, a),
                                  __builtin_bit_cast(h2_t, b), c, false);
}
__device__ __forceinline__ uint32_t pack2(float x, float y) {
    h2_t v; v[0] = (_Float16)x; v[1] = (_Float16)y;
    return __builtin_bit_cast(uint32_t, v);
}
__device__ __forceinline__ uint16_t f2h_bits(float x) {
    _Float16 h = (_Float16)x;
    return __builtin_bit_cast(uint16_t, h);
}
__device__ __forceinline__ float tanh_fast(float x) {
    // tanh(x) = 1 - 2/(exp(2x)+1); saturates correctly at +-inf
    float e = __expf(2.0f * x);
    return 1.0f - 2.0f / (e + 1.0f);
}

// ---------------- Phase 1: x_proj[b,s,:] = W_ih @ emb[idx[b,s]] + b_ih + b_hh
// Written into d_out's outputs region (same layout (B,S,H); phase 2 consumes
// xp[b,t,i] and overwrites with h[b,t,i] at the same address, read-before-write).
// Grid: 1024 WGs x 512 thr; WG owns 32 rows x all 512 cols; thread t owns col t.
__global__ __launch_bounds__(512, 4) void phase1(
    const int* __restrict__ idx, const float* __restrict__ emb,
    const float* __restrict__ Wih, const float* __restrict__ bih,
    const float* __restrict__ bhh, float* __restrict__ out) {
    __shared__ __align__(16) uint16_t xt[32][512];  // 32 KB fp16 x-tile
    const int t  = threadIdx.x;
    const int r0 = blockIdx.x * 32;

    // stage 32 gathered embedding rows -> LDS fp16 (batched loads for MLP)
    float xv[8];
    for (int rb = 0; rb < 4; ++rb) {
#pragma unroll
        for (int u = 0; u < 8; ++u) {
            int row = r0 + rb * 8 + u;
            xv[u] = emb[(size_t)idx[row] * EE + t];
        }
#pragma unroll
        for (int u = 0; u < 8; ++u)
            xt[rb * 8 + u][t] = f2h_bits(xv[u]);
    }
    float bias = bih[t] + bhh[t];
    __syncthreads();

    const float4* wrow = (const float4*)(Wih + (size_t)t * EE);
    float acc[32];
#pragma unroll
    for (int r = 0; r < 32; ++r) acc[r] = 0.0f;

    // K in chunks of 32 floats (16 fp16 dwords in regs)
    for (int c = 0; c < 16; ++c) {
        uint32_t wb[16];
        const float4* wc = wrow + c * 8;
#pragma unroll
        for (int q = 0; q < 8; ++q) {
            float4 v = wc[q];
            wb[2 * q]     = pack2(v.x, v.y);
            wb[2 * q + 1] = pack2(v.z, v.w);
        }
#pragma unroll
        for (int r = 0; r < 32; ++r) {
            const uint4* hx = (const uint4*)(&xt[r][c * 32]);
            uint4 x0 = hx[0], x1 = hx[1], x2 = hx[2], x3 = hx[3];
            float a = acc[r];
            a = fdot2(wb[0],  x0.x, a);
            a = fdot2(wb[1],  x0.y, a);
            a = fdot2(wb[2],  x0.z, a);
            a = fdot2(wb[3],  x0.w, a);
            a = fdot2(wb[4],  x1.x, a);
            a = fdot2(wb[5],  x1.y, a);
            a = fdot2(wb[6],  x1.z, a);
            a = fdot2(wb[7],  x1.w, a);
            a = fdot2(wb[8],  x2.x, a);
            a = fdot2(wb[9],  x2.y, a);
            a = fdot2(wb[10], x2.z, a);
            a = fdot2(wb[11], x2.w, a);
            a = fdot2(wb[12], x3.x, a);
            a = fdot2(wb[13], x3.y, a);
            a = fdot2(wb[14], x3.z, a);
            a = fdot2(wb[15], x3.w, a);
            acc[r] = a;
        }
    }
#pragma unroll
    for (int r = 0; r < 32; ++r)
        out[(size_t)(r0 + r) * HH + t] = acc[r] + bias;
}

// ---------------- Phase 2: 512-step recurrence. 64 WGs (1/batch, 1/CU),
// 512 threads; thread i owns row i of W_hh: 208 dwords fp16 in VGPRs +
// 48 dwords in LDS (96 KB, [k][lane] layout -> conflict-free). h ping-pong
// in LDS fp16; one barrier per step; xp prefetched one step ahead.
#define RDW 208
#define LDW 48

__global__ __launch_bounds__(512, 2) void phase2(
    const float* __restrict__ Whh, float* __restrict__ out) {
    __shared__ uint32_t wl[LDW][512];               // 96 KB
    __shared__ __align__(16) uint16_t hb[2][512];   // 2 KB ping-pong h (fp16)
    const int i = threadIdx.x;
    const int b = blockIdx.x;

    const float4* wr = (const float4*)(Whh + (size_t)i * HH);
    uint32_t wreg[RDW];
#pragma unroll
    for (int q = 0; q < RDW / 2; ++q) {             // halves 0..415 -> regs
        float4 v = wr[q];
        wreg[2 * q]     = pack2(v.x, v.y);
        wreg[2 * q + 1] = pack2(v.z, v.w);
    }
#pragma unroll
    for (int q = 0; q < LDW / 2; ++q) {             // halves 416..511 -> LDS
        float4 v = wr[RDW / 2 + q];
        wl[2 * q][i]     = pack2(v.x, v.y);
        wl[2 * q + 1][i] = pack2(v.z, v.w);
    }
    hb[0][i] = 0;                                   // h0 = 0
    __syncthreads();

    float* obase = out + (size_t)b * SS * HH + i;   // out[b,t,i] = obase[t*HH]
    float* hid   = out + (size_t)BB * SS * HH + (size_t)b * HH + i;

    float xpn = obase[0];
    float hlast = 0.0f;
    int cur = 0;
    for (int t = 0; t < SS; ++t) {
        float xp = xpn;
        if (t + 1 < SS) xpn = obase[(size_t)(t + 1) * HH];  // prefetch next xp

        const uint4* hv4 = (const uint4*)hb[cur];
        float a0 = 0.f, a1 = 0.f, a2 = 0.f, a3 = 0.f;
#pragma unroll
        for (int g = 0; g < 52; ++g) {              // reg-resident W part
            uint4 hv = hv4[g];
            a0 = fdot2(wreg[4 * g],     hv.x, a0);
            a1 = fdot2(wreg[4 * g + 1], hv.y, a1);
            a2 = fdot2(wreg[4 * g + 2], hv.z, a2);
            a3 = fdot2(wreg[4 * g + 3], hv.w, a3);
        }
#pragma unroll
        for (int g = 0; g < 12; ++g) {              // LDS-resident W part
            uint4 hv = hv4[52 + g];
            a0 = fdot2(wl[4 * g][i],     hv.x, a0);
            a1 = fdot2(wl[4 * g + 1][i], hv.y, a1);
            a2 = fdot2(wl[4 * g + 2][i], hv.z, a2);
            a3 = fdot2(wl[4 * g + 3][i], hv.w, a3);
        }
        float z = ((a0 + a1) + (a2 + a3)) + xp;
        float h = tanh_fast(z);
        obase[(size_t)t * HH] = h;                  // overwrite xp slot with h
        hb[cur ^ 1][i] = f2h_bits(h);
        hlast = h;
        cur ^= 1;
        __syncthreads();
    }
    hid[0] = hlast;                                 // final hidden state
}

extern "C" void kernel_launch(void* const* d_in, const int* in_sizes, int n_in,
                              void* d_out, int out_size, void* d_ws, size_t ws_size,
                              hipStream_t stream) {
    const int*   idx = (const int*)d_in[0];
    const float* emb = (const float*)d_in[1];
    const float* Wih = (const float*)d_in[2];
    const float* Whh = (const float*)d_in[3];
    const float* bih = (const float*)d_in[4];
    const float* bhh = (const float*)d_in[5];
    float* out = (float*)d_out;

    phase1<<<dim3(1024), dim3(512), 0, stream>>>(idx, emb, Wih, bih, bhh, out);
    phase2<<<dim3(64), dim3(512), 0, stream>>>(Whh, out);
}